// Round 2
// baseline (1021.138 us; speedup 1.0000x reference)
//
#include <hip/hip_runtime.h>
#include <hip/hip_bf16.h>

#define D 64

// ---------------------------------------------------------------------------
// Kernel 1: y = x @ W.  One wave per node row; W staged in LDS (16 KB).
// Lane j owns output feature j; x-row values broadcast via __shfl.
// ---------------------------------------------------------------------------
__global__ __launch_bounds__(256) void xw_kernel(
    const float* __restrict__ x,
    const float* __restrict__ W,
    float*       __restrict__ y,
    int nNodes)
{
    __shared__ float Wlds[D * D];
    for (int i = threadIdx.x; i < D * D; i += blockDim.x)
        Wlds[i] = W[i];
    __syncthreads();

    const int lane   = threadIdx.x & 63;
    const int wave   = (blockIdx.x * blockDim.x + threadIdx.x) >> 6;
    const int nWaves = (gridDim.x * blockDim.x) >> 6;

    for (int n = wave; n < nNodes; n += nWaves) {
        const float a = x[(size_t)n * D + lane];
        float acc = 0.f;
        #pragma unroll
        for (int k = 0; k < D; ++k)
            acc += __shfl(a, k, 64) * Wlds[k * D + lane];   // 2-way bank alias = free
        y[(size_t)n * D + lane] = acc;
    }
}

// ---------------------------------------------------------------------------
// Kernel 2: edge scatter on transformed features.
// Each wave handles 4 edges per iteration: 16 lanes per edge, float4 per lane.
// agg[dst][f] += edge_val * y[src][f]   via HW fp32 atomics (4 dwords/lane).
// ---------------------------------------------------------------------------
__global__ __launch_bounds__(256) void edge_scatter_kernel(
    const float* __restrict__ y,
    const float* __restrict__ edge_val,
    const int*   __restrict__ edge_src,
    const int*   __restrict__ edge_dst,
    float*       __restrict__ agg,
    int nEdges)
{
    const int lane   = threadIdx.x & 63;
    const int sub    = lane >> 4;          // which of 4 edges this lane serves
    const int f4     = (lane & 15) * 4;    // feature offset (float4 granularity)
    const int wave   = (blockIdx.x * blockDim.x + threadIdx.x) >> 6;
    const int nWaves = (gridDim.x * blockDim.x) >> 6;

    for (int e0 = wave * 4; e0 < nEdges; e0 += nWaves * 4) {
        const int e = e0 + sub;
        if (e < nEdges) {
            const int   s = edge_src[e];
            const int   d = edge_dst[e];
            const float v = edge_val[e];
            const float4 xv = *reinterpret_cast<const float4*>(&y[(size_t)s * D + f4]);
            float* dst = &agg[(size_t)d * D + f4];
            unsafeAtomicAdd(dst + 0, v * xv.x);
            unsafeAtomicAdd(dst + 1, v * xv.y);
            unsafeAtomicAdd(dst + 2, v * xv.z);
            unsafeAtomicAdd(dst + 3, v * xv.w);
        }
    }
}

// ---------------------------------------------------------------------------
// Kernel 3: out = relu(agg / max(||agg||_2, 1e-12)) per row.
// 4 nodes per wave, 16 lanes/node, float4 per lane.
// ---------------------------------------------------------------------------
__global__ __launch_bounds__(256) void norm_relu_kernel(
    const float* __restrict__ agg,
    float*       __restrict__ out,
    int nNodes)
{
    const int lane   = threadIdx.x & 63;
    const int sub    = lane >> 4;
    const int f4     = (lane & 15) * 4;
    const int wave   = (blockIdx.x * blockDim.x + threadIdx.x) >> 6;
    const int nWaves = (gridDim.x * blockDim.x) >> 6;

    for (int n0 = wave * 4; n0 < nNodes; n0 += nWaves * 4) {
        const int n = n0 + sub;
        float4 a = make_float4(0.f, 0.f, 0.f, 0.f);
        if (n < nNodes)
            a = *reinterpret_cast<const float4*>(&agg[(size_t)n * D + f4]);
        float ss = a.x * a.x + a.y * a.y + a.z * a.z + a.w * a.w;
        // reduce across the 16-lane group (consecutive lanes -> xor stays in group)
        ss += __shfl_xor(ss, 1, 64);
        ss += __shfl_xor(ss, 2, 64);
        ss += __shfl_xor(ss, 4, 64);
        ss += __shfl_xor(ss, 8, 64);
        const float inv = 1.f / fmaxf(sqrtf(ss), 1e-12f);
        if (n < nNodes) {
            float4 r;
            r.x = fmaxf(a.x * inv, 0.f);
            r.y = fmaxf(a.y * inv, 0.f);
            r.z = fmaxf(a.z * inv, 0.f);
            r.w = fmaxf(a.w * inv, 0.f);
            *reinterpret_cast<float4*>(&out[(size_t)n * D + f4]) = r;
        }
    }
}

extern "C" void kernel_launch(void* const* d_in, const int* in_sizes, int n_in,
                              void* d_out, int out_size, void* d_ws, size_t ws_size,
                              hipStream_t stream)
{
    const float* x        = (const float*)d_in[0];
    const float* edge_val = (const float*)d_in[1];
    const float* weight   = (const float*)d_in[2];
    const int*   edge_src = (const int*)d_in[3];
    const int*   edge_dst = (const int*)d_in[4];

    const int nNodes = in_sizes[0] / D;
    const int nEdges = in_sizes[1];

    float* y   = (float*)d_ws;                         // [nNodes, 64] x@W
    float* agg = y + (size_t)nNodes * D;               // [nNodes, 64] scatter acc
    float* out = (float*)d_out;

    // zero the scatter accumulator (ws is re-poisoned before every call)
    hipMemsetAsync(agg, 0, (size_t)nNodes * D * sizeof(float), stream);

    // 1) y = x @ W
    xw_kernel<<<2048, 256, 0, stream>>>(x, weight, y, nNodes);

    // 2) agg[dst] += ev * y[src]  (A @ (xW) == (A @ x) @ W)
    edge_scatter_kernel<<<2048, 256, 0, stream>>>(
        y, edge_val, edge_src, edge_dst, agg, nEdges);

    // 3) normalize + relu
    norm_relu_kernel<<<1024, 256, 0, stream>>>(agg, out, nNodes);
}

// Round 4
// 356.055 us; speedup vs baseline: 2.8679x; 2.8679x over previous
//
#include <hip/hip_runtime.h>
#include <hip/hip_bf16.h>

#define D 64

// ---------------------------------------------------------------------------
// 1) histogram: counts[dst]++ over all edges (int atomics, 1M total)
// ---------------------------------------------------------------------------
__global__ __launch_bounds__(256) void hist_kernel(
    const int* __restrict__ edge_dst, int* __restrict__ counts, int nEdges)
{
    int i = blockIdx.x * blockDim.x + threadIdx.x;
    int stride = gridDim.x * blockDim.x;
    for (; i < nEdges; i += stride)
        atomicAdd(&counts[edge_dst[i]], 1);
}

// ---------------------------------------------------------------------------
// 2a) per-block inclusive scan of counts -> incl, block totals -> blockSums
// ---------------------------------------------------------------------------
__global__ __launch_bounds__(256) void scanA_kernel(
    const int* __restrict__ counts, int* __restrict__ incl,
    int* __restrict__ blockSums, int n)
{
    __shared__ int buf[256];
    const int i = blockIdx.x * 256 + threadIdx.x;
    int v = (i < n) ? counts[i] : 0;
    buf[threadIdx.x] = v;
    __syncthreads();
    for (int off = 1; off < 256; off <<= 1) {
        int t = (threadIdx.x >= off) ? buf[threadIdx.x - off] : 0;
        __syncthreads();
        buf[threadIdx.x] += t;
        __syncthreads();
    }
    if (i < n) incl[i] = buf[threadIdx.x];
    if (threadIdx.x == 255) blockSums[blockIdx.x] = buf[255];
}

// ---------------------------------------------------------------------------
// 2b) exclusive scan of blockSums (single block, chunked with carry)
// ---------------------------------------------------------------------------
__global__ __launch_bounds__(1024) void scanB_kernel(int* __restrict__ bs, int nB)
{
    __shared__ int buf[1024];
    __shared__ int carry;
    if (threadIdx.x == 0) carry = 0;
    __syncthreads();
    for (int base = 0; base < nB; base += 1024) {
        const int i = base + (int)threadIdx.x;
        int v = (i < nB) ? bs[i] : 0;
        buf[threadIdx.x] = v;
        __syncthreads();
        for (int off = 1; off < 1024; off <<= 1) {
            int t = (threadIdx.x >= off) ? buf[threadIdx.x - off] : 0;
            __syncthreads();
            buf[threadIdx.x] += t;
            __syncthreads();
        }
        if (i < nB) bs[i] = buf[threadIdx.x] - v + carry;
        __syncthreads();
        if (threadIdx.x == 0) carry += buf[1023];
        __syncthreads();
    }
}

// ---------------------------------------------------------------------------
// 2c) offsets[i] = incl[i] - counts[i] + blockSums[b]; cursor = copy
// ---------------------------------------------------------------------------
__global__ __launch_bounds__(256) void scanC_kernel(
    const int* __restrict__ counts, const int* __restrict__ incl,
    const int* __restrict__ blockSums, int* __restrict__ offsets,
    int* __restrict__ cursor, int n)
{
    const int i = blockIdx.x * 256 + threadIdx.x;
    if (i < n) {
        int off = incl[i] - counts[i] + blockSums[blockIdx.x];
        offsets[i] = off;
        cursor[i]  = off;
    }
}

// ---------------------------------------------------------------------------
// 3) scatter edges into dst-sorted order; (src,val) packed as int2
// ---------------------------------------------------------------------------
__global__ __launch_bounds__(256) void scatter_kernel(
    const int*   __restrict__ edge_src,
    const int*   __restrict__ edge_dst,
    const float* __restrict__ edge_val,
    int*  __restrict__ cursor,
    int2* __restrict__ sorted_sv,
    int nEdges)
{
    int i = blockIdx.x * blockDim.x + threadIdx.x;
    int stride = gridDim.x * blockDim.x;
    for (; i < nEdges; i += stride) {
        const int d = edge_dst[i];
        const int pos = atomicAdd(&cursor[d], 1);
        sorted_sv[pos] = make_int2(edge_src[i], __float_as_int(edge_val[i]));
    }
}

// ---------------------------------------------------------------------------
// 4) fused: per node  agg = sum val*x[src]  -> @W (LDS + shfl) -> l2norm -> relu
//    One wave per node; lane = feature. 4 independent gather chains.
// ---------------------------------------------------------------------------
__global__ __launch_bounds__(256) void gather_gemv_norm_kernel(
    const float* __restrict__ x,
    const float* __restrict__ W,
    const int*   __restrict__ offsets,
    const int*   __restrict__ counts,
    const int2*  __restrict__ sorted_sv,
    float*       __restrict__ out,
    int nNodes)
{
    __shared__ float Wlds[D * D];
    for (int i = threadIdx.x; i < D * D; i += blockDim.x)
        Wlds[i] = W[i];
    __syncthreads();

    const int lane   = threadIdx.x & 63;
    const int wave   = (blockIdx.x * blockDim.x + threadIdx.x) >> 6;
    const int nWaves = (gridDim.x * blockDim.x) >> 6;

    for (int n = wave; n < nNodes; n += nWaves) {
        const int start = offsets[n];
        const int cnt   = counts[n];

        float a0 = 0.f, a1 = 0.f, a2 = 0.f, a3 = 0.f;
        int j = start;
        const int end4 = start + (cnt & ~3);
        for (; j < end4; j += 4) {
            const int2 e0 = sorted_sv[j + 0];
            const int2 e1 = sorted_sv[j + 1];
            const int2 e2 = sorted_sv[j + 2];
            const int2 e3 = sorted_sv[j + 3];
            a0 += __int_as_float(e0.y) * x[(size_t)e0.x * D + lane];
            a1 += __int_as_float(e1.y) * x[(size_t)e1.x * D + lane];
            a2 += __int_as_float(e2.y) * x[(size_t)e2.x * D + lane];
            a3 += __int_as_float(e3.y) * x[(size_t)e3.x * D + lane];
        }
        const int end = start + cnt;
        for (; j < end; ++j) {
            const int2 e = sorted_sv[j];
            a0 += __int_as_float(e.y) * x[(size_t)e.x * D + lane];
        }
        const float acc = (a0 + a1) + (a2 + a3);   // agg[n][lane]

        // o[lane] = sum_k acc_k * W[k][lane]
        float o = 0.f;
        #pragma unroll
        for (int k = 0; k < D; ++k)
            o += __shfl(acc, k, 64) * Wlds[k * D + lane]; // 2-way alias = free

        // L2 norm across 64 lanes
        float ss = o * o;
        #pragma unroll
        for (int off = 32; off; off >>= 1)
            ss += __shfl_xor(ss, off, 64);
        const float inv = 1.f / fmaxf(sqrtf(ss), 1e-12f);

        out[(size_t)n * D + lane] = fmaxf(o * inv, 0.f);
    }
}

extern "C" void kernel_launch(void* const* d_in, const int* in_sizes, int n_in,
                              void* d_out, int out_size, void* d_ws, size_t ws_size,
                              hipStream_t stream)
{
    const float* x        = (const float*)d_in[0];
    const float* edge_val = (const float*)d_in[1];
    const float* weight   = (const float*)d_in[2];
    const int*   edge_src = (const int*)d_in[3];
    const int*   edge_dst = (const int*)d_in[4];

    const int nNodes = in_sizes[0] / D;
    const int nEdges = in_sizes[1];
    const int nB     = (nNodes + 255) / 256;     // scan blocks

    // workspace layout (all within ws; re-poisoned every call)
    int*  counts    = (int*)d_ws;                  // [nNodes]
    int*  offsets   = counts  + nNodes;            // [nNodes]
    int*  cursor    = offsets + nNodes;            // [nNodes]
    int*  incl      = cursor  + nNodes;            // [nNodes]
    int*  blockSums = incl    + nNodes;            // [<=4096]
    int2* sorted_sv = (int2*)(blockSums + 4096);   // [nEdges] (src,val) pairs
    float* out      = (float*)d_out;

    // 1) zero histogram
    hipMemsetAsync(counts, 0, (size_t)nNodes * sizeof(int), stream);

    // 2) histogram
    hist_kernel<<<2048, 256, 0, stream>>>(edge_dst, counts, nEdges);

    // 3) exclusive scan -> offsets, cursor
    scanA_kernel<<<nB, 256, 0, stream>>>(counts, incl, blockSums, nNodes);
    scanB_kernel<<<1, 1024, 0, stream>>>(blockSums, nB);
    scanC_kernel<<<nB, 256, 0, stream>>>(counts, incl, blockSums, offsets, cursor, nNodes);

    // 4) bin edges by dst
    scatter_kernel<<<2048, 256, 0, stream>>>(
        edge_src, edge_dst, edge_val, cursor, sorted_sv, nEdges);

    // 5) fused gather-reduce + GEMV + normalize + relu
    gather_gemv_norm_kernel<<<2048, 256, 0, stream>>>(
        x, weight, offsets, counts, sorted_sv, out, nNodes);
}

// Round 5
// 296.150 us; speedup vs baseline: 3.4480x; 1.2023x over previous
//
#include <hip/hip_runtime.h>
#include <hip/hip_fp16.h>

#define D 64

// ---------------------------------------------------------------------------
// 1) histogram (counts[dst]++) fused with x -> fp16 conversion
// ---------------------------------------------------------------------------
__global__ __launch_bounds__(256) void hist_convert_kernel(
    const int*    __restrict__ edge_dst,
    int*          __restrict__ counts,
    int nEdges,
    const float4* __restrict__ x4,
    uint2*        __restrict__ xhq,     // packed 4x half per uint2
    int nQuads)
{
    const int tid    = blockIdx.x * blockDim.x + threadIdx.x;
    const int stride = gridDim.x * blockDim.x;

    for (int e = tid; e < nEdges; e += stride)
        atomicAdd(&counts[edge_dst[e]], 1);

    for (int q = tid; q < nQuads; q += stride) {
        const float4 v = x4[q];
        const __half2 lo = __floats2half2_rn(v.x, v.y);
        const __half2 hi = __floats2half2_rn(v.z, v.w);
        uint2 u;
        u.x = *reinterpret_cast<const unsigned*>(&lo);
        u.y = *reinterpret_cast<const unsigned*>(&hi);
        xhq[q] = u;
    }
}

// ---------------------------------------------------------------------------
// 2a) per-block inclusive scan of counts -> incl, block totals -> blockSums
// ---------------------------------------------------------------------------
__global__ __launch_bounds__(256) void scanA_kernel(
    const int* __restrict__ counts, int* __restrict__ incl,
    int* __restrict__ blockSums, int n)
{
    __shared__ int buf[256];
    const int i = blockIdx.x * 256 + threadIdx.x;
    int v = (i < n) ? counts[i] : 0;
    buf[threadIdx.x] = v;
    __syncthreads();
    for (int off = 1; off < 256; off <<= 1) {
        int t = (threadIdx.x >= off) ? buf[threadIdx.x - off] : 0;
        __syncthreads();
        buf[threadIdx.x] += t;
        __syncthreads();
    }
    if (i < n) incl[i] = buf[threadIdx.x];
    if (threadIdx.x == 255) blockSums[blockIdx.x] = buf[255];
}

// ---------------------------------------------------------------------------
// 2b) fused block-prefix + finalize: offsets[i] = incl[i]-counts[i]+prefix(b)
//     Each block reduces blockSums[0..b-1] itself (<=391 loads) — no scanB.
// ---------------------------------------------------------------------------
__global__ __launch_bounds__(256) void scanC_kernel(
    const int* __restrict__ counts, const int* __restrict__ incl,
    const int* __restrict__ blockSums, int* __restrict__ offsets,
    int* __restrict__ cursor, int n)
{
    __shared__ int red[256];
    const int b = blockIdx.x;
    int p = 0;
    for (int t = threadIdx.x; t < b; t += 256) p += blockSums[t];
    red[threadIdx.x] = p;
    __syncthreads();
    for (int off = 128; off; off >>= 1) {
        if ((int)threadIdx.x < off) red[threadIdx.x] += red[threadIdx.x + off];
        __syncthreads();
    }
    const int prefix = red[0];
    const int i = b * 256 + (int)threadIdx.x;
    if (i < n) {
        const int off = incl[i] - counts[i] + prefix;
        offsets[i] = off;
        cursor[i]  = off;
    }
}

// ---------------------------------------------------------------------------
// 3) scatter edges into dst-sorted order; (src,val) packed as int2
// ---------------------------------------------------------------------------
__global__ __launch_bounds__(256) void scatter_kernel(
    const int*   __restrict__ edge_src,
    const int*   __restrict__ edge_dst,
    const float* __restrict__ edge_val,
    int*  __restrict__ cursor,
    int2* __restrict__ sorted_sv,
    int nEdges)
{
    int i = blockIdx.x * blockDim.x + threadIdx.x;
    const int stride = gridDim.x * blockDim.x;
    for (; i < nEdges; i += stride) {
        const int d = edge_dst[i];
        const int pos = atomicAdd(&cursor[d], 1);
        sorted_sv[pos] = make_int2(edge_src[i], __float_as_int(edge_val[i]));
    }
}

// ---------------------------------------------------------------------------
// 4) fused: agg = sum val*xh[src] (fp16 gather, 128B rows) -> @W -> norm -> relu
//    One wave per node; lane = feature. Wt transposed+padded in LDS; acc staged
//    through LDS so the GEMV runs on float4 reads (33 DS ops/node vs 128).
// ---------------------------------------------------------------------------
__global__ __launch_bounds__(256) void gather_gemv_norm_kernel(
    const __half* __restrict__ xh,
    const float*  __restrict__ W,
    const int*    __restrict__ offsets,
    const int*    __restrict__ counts,
    const int2*   __restrict__ sorted_sv,
    float*        __restrict__ out,
    int nNodes)
{
    __shared__ float Wt[D][D + 4];   // Wt[j][k] = W[k][j]; stride 68 -> 8-cyc b128 floor
    __shared__ float accL[4][D];     // per-wave acc staging

    for (int i = threadIdx.x; i < D * D; i += blockDim.x) {
        const int k = i >> 6, j = i & 63;
        Wt[j][k] = W[i];
    }
    __syncthreads();

    const int lane   = threadIdx.x & 63;
    const int w      = threadIdx.x >> 6;
    const int wave   = (blockIdx.x * blockDim.x + threadIdx.x) >> 6;
    const int nWaves = (gridDim.x * blockDim.x) >> 6;

    for (int n = wave; n < nNodes; n += nWaves) {
        const int start = offsets[n];
        const int cnt   = counts[n];

        float a0 = 0.f, a1 = 0.f, a2 = 0.f, a3 = 0.f;
        int j = start;
        const int end4 = start + (cnt & ~3);
        for (; j < end4; j += 4) {              // 4 independent 128B gather chains
            const int2 e0 = sorted_sv[j + 0];
            const int2 e1 = sorted_sv[j + 1];
            const int2 e2 = sorted_sv[j + 2];
            const int2 e3 = sorted_sv[j + 3];
            a0 += __int_as_float(e0.y) * __half2float(xh[(size_t)e0.x * D + lane]);
            a1 += __int_as_float(e1.y) * __half2float(xh[(size_t)e1.x * D + lane]);
            a2 += __int_as_float(e2.y) * __half2float(xh[(size_t)e2.x * D + lane]);
            a3 += __int_as_float(e3.y) * __half2float(xh[(size_t)e3.x * D + lane]);
        }
        const int end = start + cnt;
        for (; j < end; ++j) {
            const int2 e = sorted_sv[j];
            a0 += __int_as_float(e.y) * __half2float(xh[(size_t)e.x * D + lane]);
        }
        const float acc = (a0 + a1) + (a2 + a3);   // agg[n][lane]

        // stage acc for this wave (within-wave RAW, no barrier needed)
        accL[w][lane] = acc;

        // o[lane] = sum_k acc[k] * W[k][lane] = sum_k accL[k] * Wt[lane][k]
        float o = 0.f;
        #pragma unroll
        for (int k = 0; k < D; k += 4) {
            const float4 wv = *reinterpret_cast<const float4*>(&Wt[lane][k]);
            const float4 av = *reinterpret_cast<const float4*>(&accL[w][k]); // broadcast
            o += av.x * wv.x + av.y * wv.y + av.z * wv.z + av.w * wv.w;
        }

        // L2 norm across 64 lanes
        float ss = o * o;
        #pragma unroll
        for (int off = 32; off; off >>= 1)
            ss += __shfl_xor(ss, off, 64);
        const float inv = 1.f / fmaxf(sqrtf(ss), 1e-12f);

        out[(size_t)n * D + lane] = fmaxf(o * inv, 0.f);
    }
}

extern "C" void kernel_launch(void* const* d_in, const int* in_sizes, int n_in,
                              void* d_out, int out_size, void* d_ws, size_t ws_size,
                              hipStream_t stream)
{
    const float* x        = (const float*)d_in[0];
    const float* edge_val = (const float*)d_in[1];
    const float* weight   = (const float*)d_in[2];
    const int*   edge_src = (const int*)d_in[3];
    const int*   edge_dst = (const int*)d_in[4];

    const int nNodes = in_sizes[0] / D;
    const int nEdges = in_sizes[1];
    const int nB     = (nNodes + 255) / 256;     // scan blocks
    const int nQuads = nNodes * D / 4;           // float4 quads of x

    // workspace layout (re-poisoned every call)
    int*    counts    = (int*)d_ws;                  // [nNodes]
    int*    offsets   = counts  + nNodes;            // [nNodes]
    int*    cursor    = offsets + nNodes;            // [nNodes]
    int*    incl      = cursor  + nNodes;            // [nNodes]
    int*    blockSums = incl    + nNodes;            // [<=4096]
    int2*   sorted_sv = (int2*)(blockSums + 4096);   // [nEdges] (src,val)
    __half* xh        = (__half*)(sorted_sv + nEdges); // [nNodes*D] fp16 x
    float*  out       = (float*)d_out;

    // 1) zero histogram
    hipMemsetAsync(counts, 0, (size_t)nNodes * sizeof(int), stream);

    // 2) histogram + fp16 conversion
    hist_convert_kernel<<<2048, 256, 0, stream>>>(
        edge_dst, counts, nEdges, (const float4*)x, (uint2*)xh, nQuads);

    // 3) exclusive scan -> offsets, cursor (2 kernels; scanB folded into scanC)
    scanA_kernel<<<nB, 256, 0, stream>>>(counts, incl, blockSums, nNodes);
    scanC_kernel<<<nB, 256, 0, stream>>>(counts, incl, blockSums, offsets, cursor, nNodes);

    // 4) bin edges by dst (1 edge/thread)
    scatter_kernel<<<4096, 256, 0, stream>>>(
        edge_src, edge_dst, edge_val, cursor, sorted_sv, nEdges);

    // 5) fused fp16 gather-reduce + GEMV + normalize + relu
    gather_gemv_norm_kernel<<<2048, 256, 0, stream>>>(
        xh, weight, offsets, counts, sorted_sv, out, nNodes);
}